// Round 10
// baseline (38.023 us; speedup 1.0000x reference)
//
#include <hip/hip_runtime.h>

#define BB 4096
#define NN 64
#define DD 128
#define G  4
#define P2S 36   // part2 row stride (floats): 144B rows, 16B-aligned

// Fused, G=4 rows per block (1024 blocks, 256 threads).
// R7 structure + per-row phase-2 interleave: row g-1's [1x256]@[256x128] GEMM
// runs inside iteration g, hidden under the HBM tile stream (tail-hide).
__global__ __launch_bounds__(256) void kFused(
    const float* __restrict__ stu,
    const float* __restrict__ conc,
    const float* __restrict__ nbr,
    const float* __restrict__ Ws,
    const float* __restrict__ bs,
    const float* __restrict__ Ww,
    float* __restrict__ y)
{
    const int t    = threadIdx.x;
    const int lane = t & 63;
    const int cg   = t & 31;        // float4 column group (cols cg*4..+3)
    const int g8   = t >> 5;        // half-wave group 0..7 (rows g8+8i; k-group)
    const int wv   = t >> 6;        // wave 0..3
    const int b0   = blockIdx.x * G;

    __shared__ __align__(16) float part2[NN * P2S];      // 9 KB logit partials
    __shared__ float wsm[NN];
    __shared__ float csum[G];
    __shared__ float maskh[G];
    __shared__ __align__(16) float u[G][2 * DD];         // 4 KB
    __shared__ __align__(16) float scratch[8 * DD];      // 4 KB (wsum partials, reused per g)
    __shared__ __align__(16) float scratch2[G][8 * DD];  // 16 KB (phase-2 partials)

    const float4 wb = reinterpret_cast<const float4*>(Ww + DD)[cg];  // Ww_b
    const float4* nb4 = reinterpret_cast<const float4*>(nbr);
    const float4* Ws4 = reinterpret_cast<const float4*>(Ws);         // 256 x 32 float4

    // ---- upfront: masks + u staging, one b-row per wave ----
    {
        const int b = b0 + wv;
        float cv0 = conc[(size_t)b * DD + lane];
        float cv1 = conc[(size_t)b * DD + 64 + lane];
        float sv0 = stu [(size_t)b * DD + lane];
        float sv1 = stu [(size_t)b * DD + 64 + lane];
        u[wv][lane]           = 65.0f * sv0;
        u[wv][64 + lane]      = 65.0f * sv1;
        u[wv][DD + lane]      = 64.0f * cv0;
        u[wv][DD + 64 + lane] = 64.0f * cv1;
        float cs = cv0 + cv1, ss = sv0 + sv1;
#pragma unroll
        for (int o = 1; o < 64; o <<= 1) {
            cs += __shfl_xor(cs, o);
            ss += __shfl_xor(ss, o);
        }
        if (lane == 0) {
            csum[wv]  = cs;
            maskh[wv] = (ss != 0.0f) ? 0.5f : 0.0f;
        }
    }

    // ---- pre-load tile for g=0 ----
    float4 val[8], valn[8];
#pragma unroll
    for (int i = 0; i < 8; ++i)
        val[i] = nb4[(size_t)b0 * 2048 + t + 256 * i];

    for (int g = 0; g < G; ++g) {
        // ---- A: dot4 partials -> part2 ----
#pragma unroll
        for (int i = 0; i < 8; ++i) {
            const int row = g8 + 8 * i;
            part2[row * P2S + cg] =
                val[i].x * wb.x + val[i].y * wb.y + val[i].z * wb.z + val[i].w * wb.w;
        }
        // ---- B: prefetch g+1 tile ----
        if (g < G - 1) {
#pragma unroll
            for (int i = 0; i < 8; ++i)
                valn[i] = nb4[(size_t)(b0 + g + 1) * 2048 + t + 256 * i];
        }
        __syncthreads();   // B1: part2(g) ready; scratch(g-1) ready

        // ---- C: wave0 softmax(g); threads 128..255 fold u[g-1] ----
        if (t < NN) {
            float s = 0.0f;
#pragma unroll
            for (int j = 0; j < 8; ++j) {
                const float4 p = *reinterpret_cast<const float4*>(&part2[t * P2S + j * 4]);
                s += p.x + p.y + p.z + p.w;
            }
            float m = s;
            m = fmaxf(m, __shfl_xor(m, 1));
            m = fmaxf(m, __shfl_xor(m, 2));
            m = fmaxf(m, __shfl_xor(m, 4));
            m = fmaxf(m, __shfl_xor(m, 8));
            m = fmaxf(m, __shfl_xor(m, 16));
            m = fmaxf(m, __shfl_xor(m, 32));
            float e = __expf(s - m);
            float den = e;
            den += __shfl_xor(den, 1);
            den += __shfl_xor(den, 2);
            den += __shfl_xor(den, 4);
            den += __shfl_xor(den, 8);
            den += __shfl_xor(den, 16);
            den += __shfl_xor(den, 32);
            wsm[t] = (csum[g] != 0.0f) ? (e / den) : (1.0f / 64.0f);
        } else if (t >= 128 && g > 0) {
            const int c = t - 128;
            float s = 0.0f;
#pragma unroll
            for (int k = 0; k < 8; ++k) s += scratch[k * DD + c];
            u[g - 1][DD + c] += s;
        }
        __syncthreads();   // B2: wsm(g) ready; u[g-1] folded

        // ---- D: weighted sum(g) in registers -> scratch ----
        float4 a = {0.f, 0.f, 0.f, 0.f};
#pragma unroll
        for (int i = 0; i < 8; ++i) {
            const float w = wsm[g8 + 8 * i];    // LDS broadcast
            a.x += w * val[i].x; a.y += w * val[i].y;
            a.z += w * val[i].z; a.w += w * val[i].w;
        }
        reinterpret_cast<float4*>(scratch)[g8 * 32 + cg] = a;

        // ---- E: phase-2 GEMM for row g-1 (hidden under HBM stream) ----
        if (g > 0) {
            const int r = g - 1;
            float4 acc = {0.f, 0.f, 0.f, 0.f};
#pragma unroll 8
            for (int j = 0; j < 32; ++j) {
                const int k = g8 * 32 + j;
                const float4 wq = Ws4[k * 32 + cg];     // coalesced, L2-resident
                const float ur = u[r][k];
                acc.x += ur * wq.x; acc.y += ur * wq.y;
                acc.z += ur * wq.z; acc.w += ur * wq.w;
            }
            reinterpret_cast<float4*>(scratch2[r])[g8 * 32 + cg] = acc;
        }

        if (g < G - 1) {
#pragma unroll
            for (int i = 0; i < 8; ++i) val[i] = valn[i];
        }
    }

    // ---- epilogue: fold row 3, its GEMM, then reduce + store all rows ----
    __syncthreads();       // scratch(3) visible
    if (t < DD) {
        float s = 0.0f;
#pragma unroll
        for (int k = 0; k < 8; ++k) s += scratch[k * DD + t];
        u[G - 1][DD + t] += s;
    }
    __syncthreads();       // u[3] folded
    {
        float4 acc = {0.f, 0.f, 0.f, 0.f};
#pragma unroll 8
        for (int j = 0; j < 32; ++j) {
            const int k = g8 * 32 + j;
            const float4 wq = Ws4[k * 32 + cg];
            const float ur = u[G - 1][k];
            acc.x += ur * wq.x; acc.y += ur * wq.y;
            acc.z += ur * wq.z; acc.w += ur * wq.w;
        }
        reinterpret_cast<float4*>(scratch2[G - 1])[g8 * 32 + cg] = acc;
    }
    __syncthreads();       // scratch2 complete
#pragma unroll
    for (int i = 0; i < 2; ++i) {
        const int idx = t + 256 * i;        // 0..511
        const int r = idx >> 7;
        const int c = idx & 127;
        float s = 0.0f;
#pragma unroll
        for (int k2 = 0; k2 < 8; ++k2) s += scratch2[r][k2 * DD + c];
        y[(size_t)(b0 + r) * DD + c] = (s + 65.0f * bs[c]) * maskh[r];
        const int r2 = r + 2;
        float s2 = 0.0f;
#pragma unroll
        for (int k2 = 0; k2 < 8; ++k2) s2 += scratch2[r2][k2 * DD + c];
        y[(size_t)(b0 + r2) * DD + c] = (s2 + 65.0f * bs[c]) * maskh[r2];
        break;              // loop kept for symmetry; single pass covers 4 rows
    }
}

extern "C" void kernel_launch(void* const* d_in, const int* in_sizes, int n_in,
                              void* d_out, int out_size, void* d_ws, size_t ws_size,
                              hipStream_t stream) {
    const float* stu  = (const float*)d_in[0];
    const float* conc = (const float*)d_in[1];
    const float* nbr  = (const float*)d_in[2];
    const float* Ws   = (const float*)d_in[3];
    const float* bs   = (const float*)d_in[4];
    const float* Ww   = (const float*)d_in[5];
    float* y = (float*)d_out;

    kFused<<<BB / G, 256, 0, stream>>>(stu, conc, nbr, Ws, bs, Ww, y);
}

// Round 11
// 31.262 us; speedup vs baseline: 1.2163x; 1.2163x over previous
//
#include <hip/hip_runtime.h>

#define BB 4096
#define NN 64
#define DD 128
#define G  4
#define P2S 36   // part2 row stride (floats): 144B rows, 16B-aligned

// Fused, G=4 rows per block (1024 blocks, 256 threads).
// ONE barrier per g: part2 double-buffered; softmax computed redundantly by
// every wave (8 swizzled b128 reads + 12 shfl); weights via in-wave shfl.
// Prefetch issued first each iteration; val/valn parity (no reg copies).
// Phase 2 (u @ Ws) after the loop, as R7.
__global__ __launch_bounds__(256) void kFused(
    const float* __restrict__ stu,
    const float* __restrict__ conc,
    const float* __restrict__ nbr,
    const float* __restrict__ Ws,
    const float* __restrict__ bs,
    const float* __restrict__ Ww,
    float* __restrict__ y)
{
    const int t    = threadIdx.x;
    const int lane = t & 63;
    const int cg   = t & 31;        // float4 column group (cols cg*4..+3)
    const int g8   = t >> 5;        // half-wave group 0..7 (rows g8+8i; k-group)
    const int wv   = t >> 6;        // wave 0..3
    const int b0   = blockIdx.x * G;

    __shared__ __align__(16) float part2[2][NN * P2S];   // 18 KB (double-buffered)
    __shared__ float csum[G];
    __shared__ float maskh[G];
    __shared__ __align__(16) float u[G][2 * DD];         // 4 KB
    __shared__ __align__(16) float scratch[G * 8 * DD];  // 16 KB (per-g wsum partials)

    const float4 wb = reinterpret_cast<const float4*>(Ww + DD)[cg];  // Ww_b
    const float4* nb4 = reinterpret_cast<const float4*>(nbr);
    const float4* Ws4 = reinterpret_cast<const float4*>(Ws);         // 256 x 32 float4

    // ---- upfront: masks + u staging, one b-row per wave ----
    {
        const int b = b0 + wv;
        float cv0 = conc[(size_t)b * DD + lane];
        float cv1 = conc[(size_t)b * DD + 64 + lane];
        float sv0 = stu [(size_t)b * DD + lane];
        float sv1 = stu [(size_t)b * DD + 64 + lane];
        u[wv][lane]           = 65.0f * sv0;
        u[wv][64 + lane]      = 65.0f * sv1;
        u[wv][DD + lane]      = 64.0f * cv0;
        u[wv][DD + 64 + lane] = 64.0f * cv1;
        float cs = cv0 + cv1, ss = sv0 + sv1;
#pragma unroll
        for (int o = 1; o < 64; o <<= 1) {
            cs += __shfl_xor(cs, o);
            ss += __shfl_xor(ss, o);
        }
        if (lane == 0) {
            csum[wv]  = cs;
            maskh[wv] = (ss != 0.0f) ? 0.5f : 0.0f;
        }
    }

    // ---- pre-load tile for g=0 ----
    float4 valA[8], valB[8];
#pragma unroll
    for (int i = 0; i < 8; ++i)
        valA[i] = nb4[(size_t)b0 * 2048 + t + 256 * i];

#pragma unroll
    for (int g = 0; g < G; ++g) {
        float4* valc = (g & 1) ? valB : valA;   // compile-time after unroll
        float4* valp = (g & 1) ? valA : valB;

        // ---- prefetch g+1 tile FIRST (max latency cover) ----
        if (g < G - 1) {
#pragma unroll
            for (int i = 0; i < 8; ++i)
                valp[i] = nb4[(size_t)(b0 + g + 1) * 2048 + t + 256 * i];
        }

        // ---- A: dot4 partials -> part2[g&1] ----
#pragma unroll
        for (int i = 0; i < 8; ++i) {
            const int row = g8 + 8 * i;
            part2[g & 1][row * P2S + cg] =
                valc[i].x * wb.x + valc[i].y * wb.y + valc[i].z * wb.z + valc[i].w * wb.w;
        }
        __syncthreads();                 // the ONLY barrier per g

        // ---- C: every wave reduces all 64 rows (lane=row) + softmax ----
        float s = 0.0f;
#pragma unroll
        for (int j = 0; j < 8; ++j) {
            const int jj = (j + (lane >> 3)) & 7;    // bank swizzle (stride-36 rows)
            const float4 p = *reinterpret_cast<const float4*>(
                &part2[g & 1][lane * P2S + jj * 4]);
            s += p.x + p.y + p.z + p.w;
        }
        float m = s;
        m = fmaxf(m, __shfl_xor(m, 1));
        m = fmaxf(m, __shfl_xor(m, 2));
        m = fmaxf(m, __shfl_xor(m, 4));
        m = fmaxf(m, __shfl_xor(m, 8));
        m = fmaxf(m, __shfl_xor(m, 16));
        m = fmaxf(m, __shfl_xor(m, 32));
        const float e = __expf(s - m);
        float den = e;
        den += __shfl_xor(den, 1);
        den += __shfl_xor(den, 2);
        den += __shfl_xor(den, 4);
        den += __shfl_xor(den, 8);
        den += __shfl_xor(den, 16);
        den += __shfl_xor(den, 32);
        const float wlane = (csum[g] != 0.0f) ? (e / den) : (1.0f / 64.0f);

        // ---- D: weighted sum (weights via in-wave shfl) -> per-g scratch ----
        float4 a = {0.f, 0.f, 0.f, 0.f};
#pragma unroll
        for (int i = 0; i < 8; ++i) {
            const float w = __shfl(wlane, g8 + 8 * i);
            a.x += w * valc[i].x; a.y += w * valc[i].y;
            a.z += w * valc[i].z; a.w += w * valc[i].w;
        }
        reinterpret_cast<float4*>(scratch + g * 8 * DD)[g8 * 32 + cg] = a;
    }
    __syncthreads();                     // scratch + u staging visible

    // ---- fold weighted-sum partials into u ----
#pragma unroll
    for (int it = 0; it < 2; ++it) {
        const int idx = t + 256 * it;    // 0..511
        const int gg  = idx >> 7;
        const int c   = idx & 127;
        float s2 = 0.0f;
#pragma unroll
        for (int k = 0; k < 8; ++k) s2 += scratch[gg * 8 * DD + k * DD + c];
        u[gg][DD + c] += s2;
    }
    __syncthreads();                     // u complete

    // ---- phase 2: y[b0+r] = maskh[r] * (u[r] @ Ws + 65*bs) ----
    float4 acc0 = {0,0,0,0}, acc1 = {0,0,0,0}, acc2 = {0,0,0,0}, acc3 = {0,0,0,0};
#pragma unroll 4
    for (int j = 0; j < 32; ++j) {
        const int k = g8 * 32 + j;
        float4 wq = Ws4[k * 32 + cg];    // coalesced, L2-resident
        float u0 = u[0][k], u1 = u[1][k], u2 = u[2][k], u3 = u[3][k];
        acc0.x += u0 * wq.x; acc0.y += u0 * wq.y; acc0.z += u0 * wq.z; acc0.w += u0 * wq.w;
        acc1.x += u1 * wq.x; acc1.y += u1 * wq.y; acc1.z += u1 * wq.z; acc1.w += u1 * wq.w;
        acc2.x += u2 * wq.x; acc2.y += u2 * wq.y; acc2.z += u2 * wq.z; acc2.w += u2 * wq.w;
        acc3.x += u3 * wq.x; acc3.y += u3 * wq.y; acc3.z += u3 * wq.z; acc3.w += u3 * wq.w;
    }
    {
        float4* pr = reinterpret_cast<float4*>(scratch);     // pr[g8][r][32]
        pr[(g8 * G + 0) * 32 + cg] = acc0;
        pr[(g8 * G + 1) * 32 + cg] = acc1;
        pr[(g8 * G + 2) * 32 + cg] = acc2;
        pr[(g8 * G + 3) * 32 + cg] = acc3;
    }
    __syncthreads();
#pragma unroll
    for (int i = 0; i < 2; ++i) {
        const int idx = t + 256 * i;     // 0..511
        const int r = idx >> 7;
        const int c = idx & 127;
        float s2 = 0.0f;
#pragma unroll
        for (int k2 = 0; k2 < 8; ++k2) s2 += scratch[(k2 * G + r) * DD + c];
        y[(size_t)(b0 + r) * DD + c] = (s2 + 65.0f * bs[c]) * maskh[r];
    }
}

extern "C" void kernel_launch(void* const* d_in, const int* in_sizes, int n_in,
                              void* d_out, int out_size, void* d_ws, size_t ws_size,
                              hipStream_t stream) {
    const float* stu  = (const float*)d_in[0];
    const float* conc = (const float*)d_in[1];
    const float* nbr  = (const float*)d_in[2];
    const float* Ws   = (const float*)d_in[3];
    const float* bs   = (const float*)d_in[4];
    const float* Ww   = (const float*)d_in[5];
    float* y = (float*)d_out;

    kFused<<<BB / G, 256, 0, stream>>>(stu, conc, nbr, Ws, bs, Ww, y);
}